// Round 2
// baseline (3019.465 us; speedup 1.0000x reference)
//
#include <hip/hip_runtime.h>
#include <cstdint>

#define N_A 40000
#define N_P 100000
#define N_T 20000
#define D 128
#define OUT_DIM 64
#define E_AP 500000
#define E_PT 800000

typedef __attribute__((ext_vector_type(8))) short bf16x8;
typedef __attribute__((ext_vector_type(4))) float f32x4;

static inline int ceil_div(int a, int b){ return (a + b - 1) / b; }

__device__ inline unsigned short f2bf(float f){
  uint32_t u = __builtin_bit_cast(uint32_t, f);
  uint32_t r = (u + 0x7FFFu + ((u >> 16) & 1u)) >> 16;
  return (unsigned short)r;
}
__device__ inline float bf2f(unsigned short h){
  uint32_t u = ((uint32_t)h) << 16;
  return __builtin_bit_cast(float, u);
}

// ---------------- CSR build ----------------
__global__ void hist_kernel(const int* __restrict__ dst, int E, int* __restrict__ cnt){
  int i = blockIdx.x * blockDim.x + threadIdx.x;
  if (i < E) atomicAdd(&cnt[dst[i]], 1);
}

__global__ void block_sums_kernel(const int* __restrict__ cnt, int n, int* __restrict__ bsums){
  __shared__ int red[256];
  int b = blockIdx.x, t = threadIdx.x;
  int base = b * 1024;
  int s = 0;
  for (int i = t; i < 1024; i += 256){ int idx = base + i; if (idx < n) s += cnt[idx]; }
  red[t] = s; __syncthreads();
  for (int off = 128; off > 0; off >>= 1){ if (t < off) red[t] += red[t + off]; __syncthreads(); }
  if (t == 0) bsums[b] = red[0];
}

__global__ void scan_bsums_kernel(int* bsums, int nb){
  __shared__ int sh[128];
  int t = threadIdx.x;
  int v = (t < nb) ? bsums[t] : 0;
  sh[t] = v; __syncthreads();
  int inc = v;
  for (int off = 1; off < 128; off <<= 1){
    int x = (t >= off) ? sh[t - off] : 0; __syncthreads();
    inc += x; sh[t] = inc; __syncthreads();
  }
  if (t < nb) bsums[t] = inc - v;   // exclusive
}

__global__ void scan_final_kernel(const int* __restrict__ cnt, int n, const int* __restrict__ bsums,
                                  int* __restrict__ rowptr, int E){
  __shared__ int sh[256];
  int b = blockIdx.x, t = threadIdx.x;
  int base = b * 1024 + t * 4;
  int v[4]; int s = 0;
  #pragma unroll
  for (int j = 0; j < 4; j++){ int idx = base + j; v[j] = (idx < n) ? cnt[idx] : 0; s += v[j]; }
  sh[t] = s; __syncthreads();
  int inc = s;
  for (int off = 1; off < 256; off <<= 1){
    int x = (t >= off) ? sh[t - off] : 0; __syncthreads();
    inc += x; sh[t] = inc; __syncthreads();
  }
  int run = inc - s + bsums[b];
  #pragma unroll
  for (int j = 0; j < 4; j++){ int idx = base + j; if (idx < n) rowptr[idx] = run; run += v[j]; }
  if (b == 0 && t == 0) rowptr[n] = E;
}

__global__ void cursor_inv_kernel(const int* __restrict__ rowptr, const int* __restrict__ cnt,
                                  int n, int* __restrict__ cursor, float* __restrict__ inv){
  int i = blockIdx.x * blockDim.x + threadIdx.x;
  if (i < n){
    cursor[i] = rowptr[i];
    int c = cnt[i];
    inv[i] = 1.0f / (float)(c > 0 ? c : 1);
  }
}

__global__ void fill_kernel(const int* __restrict__ src, const int* __restrict__ dst, int E,
                            int* __restrict__ cursor, int* __restrict__ eidx){
  int i = blockIdx.x * blockDim.x + threadIdx.x;
  if (i < E){
    int d = dst[i];
    int pos = atomicAdd(&cursor[d], 1);
    eidx[pos] = src[i];
  }
}

// ---------------- weight/bias combine for the paper relation pair ----------------
__global__ void combine_wr_kernel(const float* __restrict__ Wr, float* __restrict__ wrc){
  int i = blockIdx.x * blockDim.x + threadIdx.x;
  if (i < 6 * D * D){
    int sl = i >> 14; int off = i & (D * D - 1);
    wrc[i] = Wr[(size_t)(sl * 4 + 0) * D * D + off] + Wr[(size_t)(sl * 4 + 3) * D * D + off];
  }
}

__global__ void combine_bias_kernel(const float* __restrict__ bl, float* __restrict__ bcomb){
  int i = blockIdx.x * blockDim.x + threadIdx.x;
  if (i < 6 * D){
    int sl = i >> 7; int off = i & (D - 1);
    bcomb[i] = bl[(size_t)(sl * 4 + 0) * D + off] + bl[(size_t)(sl * 4 + 3) * D + off];
  }
}

// ---------------- weight split+pack into MFMA b-frag layout ----------------
// For matrix id: ids 0-23 = W_l[(s*2+l)*4+r], 24-47 = W_r[...], 48-53 = wrc[sl], 54 = lin_model_W (N=64)
// Packed: dst[( (kc*(N/16)+cf)*64 + lane )*8 + i] = bf16( W[(kc*32 + (lane>>4)*8 + i)*N + cf*16 + (lane&15)] )
// hi plane at packs + id*32768, lo plane at +16384 (u16 units).
__global__ __launch_bounds__(256)
void pack_weights_kernel(const float* __restrict__ W_l, const float* __restrict__ W_r,
                         const float* __restrict__ wrc, const float* __restrict__ linW,
                         unsigned short* __restrict__ packs){
  int id = blockIdx.x;
  const float* src; int N = 128;
  if (id < 24)      src = W_l + (size_t)id * 16384;
  else if (id < 48) src = W_r + (size_t)(id - 24) * 16384;
  else if (id < 54) src = wrc + (size_t)(id - 48) * 16384;
  else            { src = linW; N = 64; }
  unsigned short* dhi = packs + (size_t)id * 32768;
  unsigned short* dlo = dhi + 16384;
  int ncf = N / 16;
  int slots = 4 * ncf * 64;
  for (int s = threadIdx.x; s < slots; s += 256){
    int frag = s >> 6, l = s & 63;
    int kc = frag / ncf, cf = frag - kc * ncf;
    int kb = kc * 32 + ((l >> 4) * 8);
    int col = cf * 16 + (l & 15);
    bf16x8 hv, lv;
    #pragma unroll
    for (int i = 0; i < 8; ++i){
      float f = src[(size_t)(kb + i) * N + col];
      unsigned short h = f2bf(f);
      hv[i] = (short)h;
      lv[i] = (short)f2bf(f - bf2f(h));
    }
    *(bf16x8*)(dhi + (size_t)s * 8) = hv;
    *(bf16x8*)(dlo + (size_t)s * 8) = lv;
  }
}

// ---------------- mean aggregation: one wave per dst row, float4 lanes ----------------
__global__ __launch_bounds__(256)
void agg_mean_kernel(const int* __restrict__ rowptr, const int* __restrict__ eidx,
                     const float* __restrict__ inv, const float* __restrict__ xsrc,
                     float* __restrict__ out, int ndst){
  int w = (blockIdx.x * blockDim.x + threadIdx.x) >> 6;
  if (w >= ndst) return;
  int l = threadIdx.x & 63;
  int p = l >> 5, kk = l & 31;
  int beg = rowptr[w], end = rowptr[w + 1];
  float ax = 0.f, ay = 0.f, az = 0.f, aw = 0.f;
  float bx = 0.f, by = 0.f, bz = 0.f, bw = 0.f;
  int e = beg;
  for (; e + 4 <= end; e += 4){
    int sA = eidx[e + p];
    int sB = eidx[e + 2 + p];
    float4 vA = ((const float4*)(xsrc + (size_t)sA * D))[kk];
    float4 vB = ((const float4*)(xsrc + (size_t)sB * D))[kk];
    ax += vA.x; ay += vA.y; az += vA.z; aw += vA.w;
    bx += vB.x; by += vB.y; bz += vB.z; bw += vB.w;
  }
  if (e + 2 <= end){
    int s = eidx[e + p];
    float4 v = ((const float4*)(xsrc + (size_t)s * D))[kk];
    ax += v.x; ay += v.y; az += v.z; aw += v.w;
    e += 2;
  }
  if (e < end && p == 0){
    int s = eidx[e];
    float4 v = ((const float4*)(xsrc + (size_t)s * D))[kk];
    ax += v.x; ay += v.y; az += v.z; aw += v.w;
  }
  ax += bx; ay += by; az += bz; aw += bw;
  ax += __shfl_xor(ax, 32); ay += __shfl_xor(ay, 32);
  az += __shfl_xor(az, 32); aw += __shfl_xor(aw, 32);
  if (p == 0){
    float iv = inv[w];
    float4 r; r.x = ax * iv; r.y = ay * iv; r.z = az * iv; r.w = aw * iv;
    ((float4*)(out + (size_t)w * D))[kk] = r;
  }
}

// ---------------- MFMA split-bf16 GEMM ----------------
// out[M, NCF*16] = epi( sum_i in_i[M,128] @ W_i[128, NCF*16] + bias )
// Split precision: each product = Ahi*Bhi + Alo*Bhi + Ahi*Blo (3 MFMA passes).
// Block: 256 threads (4 waves), tile 64 rows; wave w owns rows [16w,16w+16).
template<int NIN, int NCF, bool RELU, bool DIV>
__global__ __launch_bounds__(256)
void gemm_mfma(const float* __restrict__ in0, const unsigned short* hi0, const unsigned short* lo0,
               const float* __restrict__ in1, const unsigned short* hi1, const unsigned short* lo1,
               const float* __restrict__ in2, const unsigned short* hi2, const unsigned short* lo2,
               const float* __restrict__ bias, const float* __restrict__ tdiv,
               float* __restrict__ out, int nrows){
  __shared__ unsigned short sA_hi[64 * 128];
  __shared__ unsigned short sA_lo[64 * 128];

  const int tid  = threadIdx.x;
  const int row0 = blockIdx.x * 64;
  const int w    = tid >> 6;
  const int l    = tid & 63;

  f32x4 acc[NCF];
  #pragma unroll
  for (int cf = 0; cf < NCF; ++cf) acc[cf] = (f32x4){0.f, 0.f, 0.f, 0.f};

  const float* ins[3]          = {in0, in1, in2};
  const unsigned short* his[3] = {hi0, hi1, hi2};
  const unsigned short* los[3] = {lo0, lo1, lo2};

  // per-thread staging coords
  const int sr = tid >> 2;     // 0..63 row
  const int sq = tid & 3;      // k-quarter (32 floats)
  // per-wave fragment coords
  const int rloc = 16 * w + (l & 15);
  const int colg = l >> 4;
  const int sw   = (rloc & 7) << 4;
  const char* aHb = (const char*)sA_hi + rloc * 256;
  const char* aLb = (const char*)sA_lo + rloc * 256;

  #pragma unroll
  for (int inp = 0; inp < NIN; ++inp){
    if (inp > 0) __syncthreads();
    // ---- stage: fp32 -> bf16 hi/lo planes in LDS (XOR-swizzled 16B chunks) ----
    {
      int gr = row0 + sr; if (gr >= nrows) gr = nrows - 1;
      const float4* g = (const float4*)(ins[inp] + (size_t)gr * 128 + sq * 32);
      char* bH = (char*)sA_hi + sr * 256;
      char* bL = (char*)sA_lo + sr * 256;
      #pragma unroll
      for (int gch = 0; gch < 4; ++gch){
        float4 va = g[2 * gch], vb = g[2 * gch + 1];
        float fs[8] = {va.x, va.y, va.z, va.w, vb.x, vb.y, vb.z, vb.w};
        bf16x8 hv, lv;
        #pragma unroll
        for (int i = 0; i < 8; ++i){
          unsigned short h = f2bf(fs[i]);
          hv[i] = (short)h;
          lv[i] = (short)f2bf(fs[i] - bf2f(h));
        }
        int bc = (sq * 64 + gch * 16) ^ ((sr & 7) << 4);
        *(bf16x8*)(bH + bc) = hv;
        *(bf16x8*)(bL + bc) = lv;
      }
    }
    __syncthreads();
    // ---- compute ----
    const bf16x8* WH = (const bf16x8*)his[inp];
    const bf16x8* WL = (const bf16x8*)los[inp];
    #pragma unroll
    for (int kc = 0; kc < 4; ++kc){
      int bc = (kc * 64 + colg * 16) ^ sw;
      bf16x8 ah = *(const bf16x8*)(aHb + bc);
      bf16x8 al = *(const bf16x8*)(aLb + bc);
      #pragma unroll
      for (int cf = 0; cf < NCF; ++cf){
        bf16x8 bh = WH[(kc * NCF + cf) * 64 + l];
        bf16x8 bl = WL[(kc * NCF + cf) * 64 + l];
        acc[cf] = __builtin_amdgcn_mfma_f32_16x16x32_bf16(ah, bh, acc[cf], 0, 0, 0);
        acc[cf] = __builtin_amdgcn_mfma_f32_16x16x32_bf16(al, bh, acc[cf], 0, 0, 0);
        acc[cf] = __builtin_amdgcn_mfma_f32_16x16x32_bf16(ah, bl, acc[cf], 0, 0, 0);
      }
    }
  }

  // ---- epilogue: D row = (l>>4)*4 + i, col = cf*16 + (l&15) ----
  #pragma unroll
  for (int cf = 0; cf < NCF; ++cf){
    int col = cf * 16 + (l & 15);
    float bv = bias[col];
    #pragma unroll
    for (int i = 0; i < 4; ++i){
      int gr = row0 + 16 * w + colg * 4 + i;
      if (gr < nrows){
        float v = acc[cf][i] + bv;
        if (RELU) v = fmaxf(v, 0.f);
        if (DIV)  v = v / tdiv[gr];
        out[(size_t)gr * (NCF * 16) + col] = v;
      }
    }
  }
}

// ---------------- temperature fold: wtc[k] = Wt[k,:]·W2 ; wtc[128] = bt·W2 + b2 ----------------
__global__ void wtc_kernel(const float* __restrict__ Wt, const float* __restrict__ bt,
                           const float* __restrict__ W2, const float* __restrict__ b2,
                           float* __restrict__ wtc){
  int k = threadIdx.x;
  if (k < 128){
    float s = 0.f;
    #pragma unroll 4
    for (int j = 0; j < 64; ++j) s += Wt[k * 64 + j] * W2[j];
    wtc[k] = s;
  }
  if (k == 0){
    float s = 0.f;
    for (int j = 0; j < 64; ++j) s += bt[j] * W2[j];
    wtc[128] = s + b2[0];
  }
}

__global__ __launch_bounds__(256)
void temp_kernel(const float* __restrict__ ta, const float* __restrict__ wtc,
                 float* __restrict__ temp, int n){
  int w = (blockIdx.x * blockDim.x + threadIdx.x) >> 6;
  if (w >= n) return;
  int l = threadIdx.x & 63;
  float2 v = ((const float2*)(ta + (size_t)w * D))[l];
  float2 c = ((const float2*)wtc)[l];
  float s = v.x * c.x + v.y * c.y;
  #pragma unroll
  for (int off = 32; off > 0; off >>= 1) s += __shfl_xor(s, off);
  if (l == 0) temp[w] = s + wtc[128];
}

// ---------------- host ----------------
extern "C" void kernel_launch(void* const* d_in, const int* in_sizes, int n_in,
                              void* d_out, int out_size, void* d_ws, size_t ws_size,
                              hipStream_t stream){
  const float* x_author    = (const float*)d_in[0];
  const float* x_paper     = (const float*)d_in[1];
  const float* x_term      = (const float*)d_in[2];
  const float* W_l         = (const float*)d_in[3];
  const float* b_l         = (const float*)d_in[4];
  const float* W_r         = (const float*)d_in[5];
  const float* lin_model_W = (const float*)d_in[6];
  const float* lin_model_b = (const float*)d_in[7];
  const float* lin_temp_W  = (const float*)d_in[8];
  const float* lin_temp_b  = (const float*)d_in[9];
  const float* lin2_W      = (const float*)d_in[10];
  const float* lin2_b      = (const float*)d_in[11];
  const int* src_ap = (const int*)d_in[12];
  const int* dst_ap = (const int*)d_in[13];
  const int* src_pa = (const int*)d_in[14];
  const int* dst_pa = (const int*)d_in[15];
  const int* src_pt = (const int*)d_in[16];
  const int* dst_pt = (const int*)d_in[17];
  const int* src_tp = (const int*)d_in[18];
  const int* dst_tp = (const int*)d_in[19];

  // ---- workspace carve ----
  char* wp = (char*)d_ws;
  auto alloc = [&](size_t bytes)->void*{
    void* r = (void*)wp; wp += (bytes + 255) & ~(size_t)255; return r;
  };
  int*   rowptr_ap = (int*)alloc((N_P + 1) * 4);
  int*   cnt_ap    = (int*)alloc(N_P * 4);
  int*   cur_ap    = (int*)alloc(N_P * 4);
  int*   eidx_ap   = (int*)alloc((size_t)E_AP * 4);
  float* inv_ap    = (float*)alloc(N_P * 4);
  int*   rowptr_pa = (int*)alloc((N_A + 1) * 4);
  int*   cnt_pa    = (int*)alloc(N_A * 4);
  int*   cur_pa    = (int*)alloc(N_A * 4);
  int*   eidx_pa   = (int*)alloc((size_t)E_AP * 4);
  float* inv_pa    = (float*)alloc(N_A * 4);
  int*   rowptr_pt = (int*)alloc((N_T + 1) * 4);
  int*   cnt_pt    = (int*)alloc(N_T * 4);
  int*   cur_pt    = (int*)alloc(N_T * 4);
  int*   eidx_pt   = (int*)alloc((size_t)E_PT * 4);
  float* inv_pt    = (float*)alloc(N_T * 4);
  int*   rowptr_tp = (int*)alloc((N_P + 1) * 4);
  int*   cnt_tp    = (int*)alloc(N_P * 4);
  int*   cur_tp    = (int*)alloc(N_P * 4);
  int*   eidx_tp   = (int*)alloc((size_t)E_PT * 4);
  float* inv_tp    = (float*)alloc(N_P * 4);
  int*   bsums     = (int*)alloc(1024 * 4);
  float* A0    = (float*)alloc((size_t)N_A * D * 4);
  float* A1    = (float*)alloc((size_t)N_A * D * 4);
  float* TA    = (float*)alloc((size_t)N_A * D * 4);
  float* aggA  = (float*)alloc((size_t)N_A * D * 4);
  float* P0    = (float*)alloc((size_t)N_P * D * 4);
  float* P1    = (float*)alloc((size_t)N_P * D * 4);
  float* aggP1 = (float*)alloc((size_t)N_P * D * 4);
  float* aggP2 = (float*)alloc((size_t)N_P * D * 4);
  float* T0    = (float*)alloc((size_t)N_T * D * 4);
  float* T1    = (float*)alloc((size_t)N_T * D * 4);
  float* aggT  = (float*)alloc((size_t)N_T * D * 4);
  float* wrc   = (float*)alloc((size_t)6 * D * D * 4);
  float* bcomb = (float*)alloc((size_t)6 * D * 4);
  unsigned short* packs = (unsigned short*)alloc((size_t)55 * 32768 * 2);
  float* wtc   = (float*)alloc(129 * 4);
  float* temp  = (float*)alloc((size_t)N_A * 4);

  // ---- build CSR for the 4 relations ----
  auto build = [&](const int* src, const int* dst, int E, int n,
                   int* rowptr, int* cnt, int* cursor, int* eidx, float* inv){
    hipMemsetAsync(cnt, 0, (size_t)n * 4, stream);
    hist_kernel<<<ceil_div(E, 256), 256, 0, stream>>>(dst, E, cnt);
    int nb = ceil_div(n, 1024);
    block_sums_kernel<<<nb, 256, 0, stream>>>(cnt, n, bsums);
    scan_bsums_kernel<<<1, 128, 0, stream>>>(bsums, nb);
    scan_final_kernel<<<nb, 256, 0, stream>>>(cnt, n, bsums, rowptr, E);
    cursor_inv_kernel<<<ceil_div(n, 256), 256, 0, stream>>>(rowptr, cnt, n, cursor, inv);
    fill_kernel<<<ceil_div(E, 256), 256, 0, stream>>>(src, dst, E, cursor, eidx);
  };
  build(src_ap, dst_ap, E_AP, N_P, rowptr_ap, cnt_ap, cur_ap, eidx_ap, inv_ap);
  build(src_pa, dst_pa, E_AP, N_A, rowptr_pa, cnt_pa, cur_pa, eidx_pa, inv_pa);
  build(src_pt, dst_pt, E_PT, N_T, rowptr_pt, cnt_pt, cur_pt, eidx_pt, inv_pt);
  build(src_tp, dst_tp, E_PT, N_P, rowptr_tp, cnt_tp, cur_tp, eidx_tp, inv_tp);

  combine_wr_kernel<<<ceil_div(6 * D * D, 256), 256, 0, stream>>>(W_r, wrc);
  combine_bias_kernel<<<ceil_div(6 * D, 256), 256, 0, stream>>>(b_l, bcomb);
  pack_weights_kernel<<<55, 256, 0, stream>>>(W_l, W_r, wrc, lin_model_W, packs);
  wtc_kernel<<<1, 128, 0, stream>>>(lin_temp_W, lin_temp_b, lin2_W, lin2_b, wtc);

  auto HI = [&](int id){ return packs + (size_t)id * 32768; };
  auto LO = [&](int id){ return packs + (size_t)id * 32768 + 16384; };
  auto IDL = [&](int s, int l, int r){ return (s * 2 + l) * 4 + r; };
  auto IDR = [&](int s, int l, int r){ return 24 + (s * 2 + l) * 4 + r; };
  auto IDC = [&](int s, int l){ return 48 + s * 2 + l; };
  auto Bl  = [&](int s, int l, int r){ return b_l + (size_t)((s * 2 + l) * 4 + r) * D; };
  auto BC  = [&](int s, int l){ return bcomb + (size_t)(s * 2 + l) * D; };

  auto agg = [&](const int* rowptr, const int* eidx, const float* inv,
                 const float* xsrc, float* outp, int ndst){
    agg_mean_kernel<<<ceil_div(ndst, 4), 256, 0, stream>>>(rowptr, eidx, inv, xsrc, outp, ndst);
  };

  auto layer = [&](const float* ia, const float* ip, const float* it, int s, int l,
                   float* oa, float* op, float* ot){
    if (op){
      agg(rowptr_ap, eidx_ap, inv_ap, ia, aggP1, N_P);
      agg(rowptr_tp, eidx_tp, inv_tp, it, aggP2, N_P);
      gemm_mfma<3, 8, true, false><<<ceil_div(N_P, 64), 256, 0, stream>>>(
          aggP1, HI(IDL(s, l, 0)), LO(IDL(s, l, 0)),
          aggP2, HI(IDL(s, l, 3)), LO(IDL(s, l, 3)),
          ip,    HI(IDC(s, l)),    LO(IDC(s, l)),
          BC(s, l), nullptr, op, N_P);
    }
    if (oa){
      agg(rowptr_pa, eidx_pa, inv_pa, ip, aggA, N_A);
      gemm_mfma<2, 8, true, false><<<ceil_div(N_A, 64), 256, 0, stream>>>(
          aggA, HI(IDL(s, l, 1)), LO(IDL(s, l, 1)),
          ia,   HI(IDR(s, l, 1)), LO(IDR(s, l, 1)),
          nullptr, nullptr, nullptr,
          Bl(s, l, 1), nullptr, oa, N_A);
    }
    if (ot){
      agg(rowptr_pt, eidx_pt, inv_pt, ip, aggT, N_T);
      gemm_mfma<2, 8, true, false><<<ceil_div(N_T, 64), 256, 0, stream>>>(
          aggT, HI(IDL(s, l, 2)), LO(IDL(s, l, 2)),
          it,   HI(IDR(s, l, 2)), LO(IDR(s, l, 2)),
          nullptr, nullptr, nullptr,
          Bl(s, l, 2), nullptr, ot, N_T);
    }
  };

  float* out_logits = (float*)d_out;
  float* out_oa = out_logits + (size_t)N_A * OUT_DIM;
  float* out_op = out_oa + (size_t)N_A * D;
  float* out_ot = out_op + (size_t)N_P * D;

  // stack 0 (model) on raw features -> ma,mp,mt in A0,P0,T0
  layer(x_author, x_paper, x_term, 0, 0, A1, P1, T1);
  layer(A1, P1, T1, 0, 1, A0, P0, T0);
  // stack 1 (temperature) on ma,mp,mt; only author output of layer 1 needed
  layer(A0, P0, T0, 1, 0, A1, P1, T1);
  layer(A1, P1, T1, 1, 1, TA, nullptr, nullptr);
  // stack 2 (convs) on raw features -> directly into d_out
  layer(x_author, x_paper, x_term, 2, 0, A1, P1, T1);
  layer(A1, P1, T1, 2, 1, out_oa, out_op, out_ot);
  // temperature scalar per author, then logits GEMM with divide epilogue
  temp_kernel<<<ceil_div(N_A, 4), 256, 0, stream>>>(TA, wtc, temp, N_A);
  gemm_mfma<1, 4, false, true><<<ceil_div(N_A, 64), 256, 0, stream>>>(
      A0, HI(54), LO(54),
      nullptr, nullptr, nullptr,
      nullptr, nullptr, nullptr,
      lin_model_b, temp, out_logits, N_A);
}

// Round 3
// 2451.808 us; speedup vs baseline: 1.2315x; 1.2315x over previous
//
#include <hip/hip_runtime.h>
#include <cstdint>

#define N_A 40000
#define N_P 100000
#define N_T 20000
#define D 128
#define OUT_DIM 64
#define E_AP 500000
#define E_PT 800000

typedef __attribute__((ext_vector_type(8))) short bf16x8;
typedef __attribute__((ext_vector_type(4))) float f32x4;

static inline int ceil_div(int a, int b){ return (a + b - 1) / b; }

__device__ inline unsigned short f2bf(float f){
  uint32_t u = __builtin_bit_cast(uint32_t, f);
  uint32_t r = (u + 0x7FFFu + ((u >> 16) & 1u)) >> 16;
  return (unsigned short)r;
}
__device__ inline float bf2f(unsigned short h){
  uint32_t u = ((uint32_t)h) << 16;
  return __builtin_bit_cast(float, u);
}

// ---------------- CSR build ----------------
__global__ void hist_kernel(const int* __restrict__ dst, int E, int* __restrict__ cnt){
  int i = blockIdx.x * blockDim.x + threadIdx.x;
  if (i < E) atomicAdd(&cnt[dst[i]], 1);
}

__global__ void block_sums_kernel(const int* __restrict__ cnt, int n, int* __restrict__ bsums){
  __shared__ int red[256];
  int b = blockIdx.x, t = threadIdx.x;
  int base = b * 1024;
  int s = 0;
  for (int i = t; i < 1024; i += 256){ int idx = base + i; if (idx < n) s += cnt[idx]; }
  red[t] = s; __syncthreads();
  for (int off = 128; off > 0; off >>= 1){ if (t < off) red[t] += red[t + off]; __syncthreads(); }
  if (t == 0) bsums[b] = red[0];
}

__global__ void scan_bsums_kernel(int* bsums, int nb){
  __shared__ int sh[128];
  int t = threadIdx.x;
  int v = (t < nb) ? bsums[t] : 0;
  sh[t] = v; __syncthreads();
  int inc = v;
  for (int off = 1; off < 128; off <<= 1){
    int x = (t >= off) ? sh[t - off] : 0; __syncthreads();
    inc += x; sh[t] = inc; __syncthreads();
  }
  if (t < nb) bsums[t] = inc - v;   // exclusive
}

__global__ void scan_final_kernel(const int* __restrict__ cnt, int n, const int* __restrict__ bsums,
                                  int* __restrict__ rowptr, int E){
  __shared__ int sh[256];
  int b = blockIdx.x, t = threadIdx.x;
  int base = b * 1024 + t * 4;
  int v[4]; int s = 0;
  #pragma unroll
  for (int j = 0; j < 4; j++){ int idx = base + j; v[j] = (idx < n) ? cnt[idx] : 0; s += v[j]; }
  sh[t] = s; __syncthreads();
  int inc = s;
  for (int off = 1; off < 256; off <<= 1){
    int x = (t >= off) ? sh[t - off] : 0; __syncthreads();
    inc += x; sh[t] = inc; __syncthreads();
  }
  int run = inc - s + bsums[b];
  #pragma unroll
  for (int j = 0; j < 4; j++){ int idx = base + j; if (idx < n) rowptr[idx] = run; run += v[j]; }
  if (b == 0 && t == 0) rowptr[n] = E;
}

__global__ void cursor_inv_kernel(const int* __restrict__ rowptr, const int* __restrict__ cnt,
                                  int n, int* __restrict__ cursor, float* __restrict__ inv){
  int i = blockIdx.x * blockDim.x + threadIdx.x;
  if (i < n){
    cursor[i] = rowptr[i];
    int c = cnt[i];
    inv[i] = 1.0f / (float)(c > 0 ? c : 1);
  }
}

__global__ void fill_kernel(const int* __restrict__ src, const int* __restrict__ dst, int E,
                            int* __restrict__ cursor, int* __restrict__ eidx){
  int i = blockIdx.x * blockDim.x + threadIdx.x;
  if (i < E){
    int d = dst[i];
    int pos = atomicAdd(&cursor[d], 1);
    eidx[pos] = src[i];
  }
}

// ---------------- weight/bias combine for the paper relation pair ----------------
__global__ void combine_wr_kernel(const float* __restrict__ Wr, float* __restrict__ wrc){
  int i = blockIdx.x * blockDim.x + threadIdx.x;
  if (i < 6 * D * D){
    int sl = i >> 14; int off = i & (D * D - 1);
    wrc[i] = Wr[(size_t)(sl * 4 + 0) * D * D + off] + Wr[(size_t)(sl * 4 + 3) * D * D + off];
  }
}

__global__ void combine_bias_kernel(const float* __restrict__ bl, float* __restrict__ bcomb){
  int i = blockIdx.x * blockDim.x + threadIdx.x;
  if (i < 6 * D){
    int sl = i >> 7; int off = i & (D - 1);
    bcomb[i] = bl[(size_t)(sl * 4 + 0) * D + off] + bl[(size_t)(sl * 4 + 3) * D + off];
  }
}

// ---------------- weight split+pack into MFMA b-frag layout ----------------
// ids 0-23 = W_l, 24-47 = W_r, 48-53 = wrc, 54 = lin_model_W (N=64)
// dst[((kc*(N/16)+cf)*64 + lane)*8 + i] = bf16(W[(kc*32+(lane>>4)*8+i)*N + cf*16+(lane&15)])
__global__ __launch_bounds__(256)
void pack_weights_kernel(const float* __restrict__ W_l, const float* __restrict__ W_r,
                         const float* __restrict__ wrc, const float* __restrict__ linW,
                         unsigned short* __restrict__ packs){
  int id = blockIdx.x;
  const float* src; int N = 128;
  if (id < 24)      src = W_l + (size_t)id * 16384;
  else if (id < 48) src = W_r + (size_t)(id - 24) * 16384;
  else if (id < 54) src = wrc + (size_t)(id - 48) * 16384;
  else            { src = linW; N = 64; }
  unsigned short* dhi = packs + (size_t)id * 32768;
  unsigned short* dlo = dhi + 16384;
  int ncf = N / 16;
  int slots = 4 * ncf * 64;
  for (int s = threadIdx.x; s < slots; s += 256){
    int frag = s >> 6, l = s & 63;
    int kc = frag / ncf, cf = frag - kc * ncf;
    int kb = kc * 32 + ((l >> 4) * 8);
    int col = cf * 16 + (l & 15);
    bf16x8 hv, lv;
    #pragma unroll
    for (int i = 0; i < 8; ++i){
      float f = src[(size_t)(kb + i) * N + col];
      unsigned short h = f2bf(f);
      hv[i] = (short)h;
      lv[i] = (short)f2bf(f - bf2f(h));
    }
    *(bf16x8*)(dhi + (size_t)s * 8) = hv;
    *(bf16x8*)(dlo + (size_t)s * 8) = lv;
  }
}

// ---------------- mean aggregation: one wave per dst row, 8 edges in flight ----------------
__global__ __launch_bounds__(256)
void agg_mean_kernel(const int* __restrict__ rowptr, const int* __restrict__ eidx,
                     const float* __restrict__ inv, const float* __restrict__ xsrc,
                     float* __restrict__ out, int ndst){
  int w = (blockIdx.x * blockDim.x + threadIdx.x) >> 6;
  if (w >= ndst) return;
  int l = threadIdx.x & 63;
  int p = l >> 5, kk = l & 31;
  int beg = rowptr[w], end = rowptr[w + 1];
  float4 a0 = make_float4(0,0,0,0), a1 = make_float4(0,0,0,0);
  float4 a2 = make_float4(0,0,0,0), a3 = make_float4(0,0,0,0);
  int e = beg;
  for (; e + 8 <= end; e += 8){
    int s0 = eidx[e + p], s1 = eidx[e + 2 + p], s2 = eidx[e + 4 + p], s3 = eidx[e + 6 + p];
    float4 v0 = ((const float4*)(xsrc + (size_t)s0 * D))[kk];
    float4 v1 = ((const float4*)(xsrc + (size_t)s1 * D))[kk];
    float4 v2 = ((const float4*)(xsrc + (size_t)s2 * D))[kk];
    float4 v3 = ((const float4*)(xsrc + (size_t)s3 * D))[kk];
    a0.x += v0.x; a0.y += v0.y; a0.z += v0.z; a0.w += v0.w;
    a1.x += v1.x; a1.y += v1.y; a1.z += v1.z; a1.w += v1.w;
    a2.x += v2.x; a2.y += v2.y; a2.z += v2.z; a2.w += v2.w;
    a3.x += v3.x; a3.y += v3.y; a3.z += v3.z; a3.w += v3.w;
  }
  if (e + 4 <= end){
    int s0 = eidx[e + p], s1 = eidx[e + 2 + p];
    float4 v0 = ((const float4*)(xsrc + (size_t)s0 * D))[kk];
    float4 v1 = ((const float4*)(xsrc + (size_t)s1 * D))[kk];
    a0.x += v0.x; a0.y += v0.y; a0.z += v0.z; a0.w += v0.w;
    a1.x += v1.x; a1.y += v1.y; a1.z += v1.z; a1.w += v1.w;
    e += 4;
  }
  if (e + 2 <= end){
    int s0 = eidx[e + p];
    float4 v0 = ((const float4*)(xsrc + (size_t)s0 * D))[kk];
    a0.x += v0.x; a0.y += v0.y; a0.z += v0.z; a0.w += v0.w;
    e += 2;
  }
  if (e < end && p == 0){
    int s0 = eidx[e];
    float4 v0 = ((const float4*)(xsrc + (size_t)s0 * D))[kk];
    a0.x += v0.x; a0.y += v0.y; a0.z += v0.z; a0.w += v0.w;
  }
  a0.x += a1.x + a2.x + a3.x; a0.y += a1.y + a2.y + a3.y;
  a0.z += a1.z + a2.z + a3.z; a0.w += a1.w + a2.w + a3.w;
  a0.x += __shfl_xor(a0.x, 32); a0.y += __shfl_xor(a0.y, 32);
  a0.z += __shfl_xor(a0.z, 32); a0.w += __shfl_xor(a0.w, 32);
  if (p == 0){
    float iv = inv[w];
    float4 r; r.x = a0.x * iv; r.y = a0.y * iv; r.z = a0.z * iv; r.w = a0.w * iv;
    ((float4*)(out + (size_t)w * D))[kk] = r;
  }
}

// ---------------- MFMA split-bf16 GEMM, LDS-free ----------------
// out[M, NCF*16] = epi( sum_i in_i[M,128] @ W_i[128, NCF*16] + bias )
// product = Ahi*Bhi + Alo*Bhi + Ahi*Blo (truncation split).
// Block: 256 threads / 4 waves; wave owns 32 rows (2 row-frags); tile M = 128/block.
template<int NIN, int NCF, bool RELU, bool DIV>
__global__ __launch_bounds__(256)
void gemm_mfma(const float* __restrict__ in0, const unsigned short* hi0, const unsigned short* lo0,
               const float* __restrict__ in1, const unsigned short* hi1, const unsigned short* lo1,
               const float* __restrict__ in2, const unsigned short* hi2, const unsigned short* lo2,
               const float* __restrict__ bias, const float* __restrict__ tdiv,
               float* __restrict__ out, int nrows){
  const int tid  = threadIdx.x;
  const int w    = tid >> 6;
  const int l    = tid & 63;
  const int lane15 = l & 15;
  const int colg   = l >> 4;
  const int rbase  = blockIdx.x * 128 + w * 32;

  f32x4 acc[2][NCF];
  #pragma unroll
  for (int m = 0; m < 2; ++m)
    #pragma unroll
    for (int cf = 0; cf < NCF; ++cf) acc[m][cf] = (f32x4){0.f, 0.f, 0.f, 0.f};

  const float* ins[3]          = {in0, in1, in2};
  const unsigned short* his[3] = {hi0, hi1, hi2};
  const unsigned short* los[3] = {lo0, lo1, lo2};

  #pragma unroll
  for (int inp = 0; inp < NIN; ++inp){
    const float* A = ins[inp];
    const bf16x8* WH = (const bf16x8*)his[inp];
    const bf16x8* WL = (const bf16x8*)los[inp];
    #pragma unroll
    for (int kc = 0; kc < 4; ++kc){
      bf16x8 ah[2], al[2];
      #pragma unroll
      for (int m = 0; m < 2; ++m){
        int gr = rbase + m * 16 + lane15; if (gr >= nrows) gr = nrows - 1;
        const float4* p = (const float4*)(A + (size_t)gr * 128 + kc * 32 + colg * 8);
        float4 v0 = p[0], v1 = p[1];
        float fs[8] = {v0.x, v0.y, v0.z, v0.w, v1.x, v1.y, v1.z, v1.w};
        #pragma unroll
        for (int i = 0; i < 8; ++i){
          uint32_t u = __builtin_bit_cast(uint32_t, fs[i]);
          unsigned short h = (unsigned short)(u >> 16);            // truncation split
          float r = fs[i] - __builtin_bit_cast(float, u & 0xFFFF0000u);
          ah[m][i] = (short)h;
          al[m][i] = (short)(__builtin_bit_cast(uint32_t, r) >> 16);
        }
      }
      #pragma unroll
      for (int cf = 0; cf < NCF; ++cf){
        bf16x8 bh = WH[(kc * NCF + cf) * 64 + l];
        bf16x8 bl = WL[(kc * NCF + cf) * 64 + l];
        #pragma unroll
        for (int m = 0; m < 2; ++m){
          acc[m][cf] = __builtin_amdgcn_mfma_f32_16x16x32_bf16(ah[m], bh, acc[m][cf], 0, 0, 0);
          acc[m][cf] = __builtin_amdgcn_mfma_f32_16x16x32_bf16(al[m], bh, acc[m][cf], 0, 0, 0);
          acc[m][cf] = __builtin_amdgcn_mfma_f32_16x16x32_bf16(ah[m], bl, acc[m][cf], 0, 0, 0);
        }
      }
    }
  }

  // epilogue: D row = colg*4 + i (within frag), col = cf*16 + lane15
  #pragma unroll
  for (int cf = 0; cf < NCF; ++cf){
    int col = cf * 16 + lane15;
    float bv = bias[col];
    #pragma unroll
    for (int m = 0; m < 2; ++m){
      #pragma unroll
      for (int i = 0; i < 4; ++i){
        int gr = rbase + m * 16 + colg * 4 + i;
        if (gr < nrows){
          float v = acc[m][cf][i] + bv;
          if (RELU) v = fmaxf(v, 0.f);
          if (DIV)  v = v / tdiv[gr];
          out[(size_t)gr * (NCF * 16) + col] = v;
        }
      }
    }
  }
}

// ---------------- temperature fold ----------------
__global__ void wtc_kernel(const float* __restrict__ Wt, const float* __restrict__ bt,
                           const float* __restrict__ W2, const float* __restrict__ b2,
                           float* __restrict__ wtc){
  int k = threadIdx.x;
  if (k < 128){
    float s = 0.f;
    #pragma unroll 4
    for (int j = 0; j < 64; ++j) s += Wt[k * 64 + j] * W2[j];
    wtc[k] = s;
  }
  if (k == 0){
    float s = 0.f;
    for (int j = 0; j < 64; ++j) s += bt[j] * W2[j];
    wtc[128] = s + b2[0];
  }
}

__global__ __launch_bounds__(256)
void temp_kernel(const float* __restrict__ ta, const float* __restrict__ wtc,
                 float* __restrict__ temp, int n){
  int w = (blockIdx.x * blockDim.x + threadIdx.x) >> 6;
  if (w >= n) return;
  int l = threadIdx.x & 63;
  float2 v = ((const float2*)(ta + (size_t)w * D))[l];
  float2 c = ((const float2*)wtc)[l];
  float s = v.x * c.x + v.y * c.y;
  #pragma unroll
  for (int off = 32; off > 0; off >>= 1) s += __shfl_xor(s, off);
  if (l == 0) temp[w] = s + wtc[128];
}

// ---------------- host ----------------
extern "C" void kernel_launch(void* const* d_in, const int* in_sizes, int n_in,
                              void* d_out, int out_size, void* d_ws, size_t ws_size,
                              hipStream_t stream){
  const float* x_author    = (const float*)d_in[0];
  const float* x_paper     = (const float*)d_in[1];
  const float* x_term      = (const float*)d_in[2];
  const float* W_l         = (const float*)d_in[3];
  const float* b_l         = (const float*)d_in[4];
  const float* W_r         = (const float*)d_in[5];
  const float* lin_model_W = (const float*)d_in[6];
  const float* lin_model_b = (const float*)d_in[7];
  const float* lin_temp_W  = (const float*)d_in[8];
  const float* lin_temp_b  = (const float*)d_in[9];
  const float* lin2_W      = (const float*)d_in[10];
  const float* lin2_b      = (const float*)d_in[11];
  const int* src_ap = (const int*)d_in[12];
  const int* dst_ap = (const int*)d_in[13];
  const int* src_pa = (const int*)d_in[14];
  const int* dst_pa = (const int*)d_in[15];
  const int* src_pt = (const int*)d_in[16];
  const int* dst_pt = (const int*)d_in[17];
  const int* src_tp = (const int*)d_in[18];
  const int* dst_tp = (const int*)d_in[19];

  // ---- workspace carve ----
  char* wp = (char*)d_ws;
  auto alloc = [&](size_t bytes)->void*{
    void* r = (void*)wp; wp += (bytes + 255) & ~(size_t)255; return r;
  };
  int*   rowptr_ap = (int*)alloc((N_P + 1) * 4);
  int*   cnt_ap    = (int*)alloc(N_P * 4);
  int*   cur_ap    = (int*)alloc(N_P * 4);
  int*   eidx_ap   = (int*)alloc((size_t)E_AP * 4);
  float* inv_ap    = (float*)alloc(N_P * 4);
  int*   rowptr_pa = (int*)alloc((N_A + 1) * 4);
  int*   cnt_pa    = (int*)alloc(N_A * 4);
  int*   cur_pa    = (int*)alloc(N_A * 4);
  int*   eidx_pa   = (int*)alloc((size_t)E_AP * 4);
  float* inv_pa    = (float*)alloc(N_A * 4);
  int*   rowptr_pt = (int*)alloc((N_T + 1) * 4);
  int*   cnt_pt    = (int*)alloc(N_T * 4);
  int*   cur_pt    = (int*)alloc(N_T * 4);
  int*   eidx_pt   = (int*)alloc((size_t)E_PT * 4);
  float* inv_pt    = (float*)alloc(N_T * 4);
  int*   rowptr_tp = (int*)alloc((N_P + 1) * 4);
  int*   cnt_tp    = (int*)alloc(N_P * 4);
  int*   cur_tp    = (int*)alloc(N_P * 4);
  int*   eidx_tp   = (int*)alloc((size_t)E_PT * 4);
  float* inv_tp    = (float*)alloc(N_P * 4);
  int*   bsums     = (int*)alloc(1024 * 4);
  float* A0    = (float*)alloc((size_t)N_A * D * 4);
  float* A1    = (float*)alloc((size_t)N_A * D * 4);
  float* TA    = (float*)alloc((size_t)N_A * D * 4);
  float* aggA  = (float*)alloc((size_t)N_A * D * 4);
  float* P0    = (float*)alloc((size_t)N_P * D * 4);
  float* P1    = (float*)alloc((size_t)N_P * D * 4);
  float* aggP1 = (float*)alloc((size_t)N_P * D * 4);
  float* aggP2 = (float*)alloc((size_t)N_P * D * 4);
  float* T0    = (float*)alloc((size_t)N_T * D * 4);
  float* T1    = (float*)alloc((size_t)N_T * D * 4);
  float* aggT  = (float*)alloc((size_t)N_T * D * 4);
  float* wrc   = (float*)alloc((size_t)6 * D * D * 4);
  float* bcomb = (float*)alloc((size_t)6 * D * 4);
  unsigned short* packs = (unsigned short*)alloc((size_t)55 * 32768 * 2);
  float* wtc   = (float*)alloc(129 * 4);
  float* temp  = (float*)alloc((size_t)N_A * 4);

  // ---- build CSR for the 4 relations ----
  auto build = [&](const int* src, const int* dst, int E, int n,
                   int* rowptr, int* cnt, int* cursor, int* eidx, float* inv){
    hipMemsetAsync(cnt, 0, (size_t)n * 4, stream);
    hist_kernel<<<ceil_div(E, 256), 256, 0, stream>>>(dst, E, cnt);
    int nb = ceil_div(n, 1024);
    block_sums_kernel<<<nb, 256, 0, stream>>>(cnt, n, bsums);
    scan_bsums_kernel<<<1, 128, 0, stream>>>(bsums, nb);
    scan_final_kernel<<<nb, 256, 0, stream>>>(cnt, n, bsums, rowptr, E);
    cursor_inv_kernel<<<ceil_div(n, 256), 256, 0, stream>>>(rowptr, cnt, n, cursor, inv);
    fill_kernel<<<ceil_div(E, 256), 256, 0, stream>>>(src, dst, E, cursor, eidx);
  };
  build(src_ap, dst_ap, E_AP, N_P, rowptr_ap, cnt_ap, cur_ap, eidx_ap, inv_ap);
  build(src_pa, dst_pa, E_AP, N_A, rowptr_pa, cnt_pa, cur_pa, eidx_pa, inv_pa);
  build(src_pt, dst_pt, E_PT, N_T, rowptr_pt, cnt_pt, cur_pt, eidx_pt, inv_pt);
  build(src_tp, dst_tp, E_PT, N_P, rowptr_tp, cnt_tp, cur_tp, eidx_tp, inv_tp);

  combine_wr_kernel<<<ceil_div(6 * D * D, 256), 256, 0, stream>>>(W_r, wrc);
  combine_bias_kernel<<<ceil_div(6 * D, 256), 256, 0, stream>>>(b_l, bcomb);
  pack_weights_kernel<<<55, 256, 0, stream>>>(W_l, W_r, wrc, lin_model_W, packs);
  wtc_kernel<<<1, 128, 0, stream>>>(lin_temp_W, lin_temp_b, lin2_W, lin2_b, wtc);

  auto HI = [&](int id){ return packs + (size_t)id * 32768; };
  auto LO = [&](int id){ return packs + (size_t)id * 32768 + 16384; };
  auto IDL = [&](int s, int l, int r){ return (s * 2 + l) * 4 + r; };
  auto IDR = [&](int s, int l, int r){ return 24 + (s * 2 + l) * 4 + r; };
  auto IDC = [&](int s, int l){ return 48 + s * 2 + l; };
  auto Bl  = [&](int s, int l, int r){ return b_l + (size_t)((s * 2 + l) * 4 + r) * D; };
  auto BC  = [&](int s, int l){ return bcomb + (size_t)(s * 2 + l) * D; };

  auto agg = [&](const int* rowptr, const int* eidx, const float* inv,
                 const float* xsrc, float* outp, int ndst){
    agg_mean_kernel<<<ceil_div(ndst, 4), 256, 0, stream>>>(rowptr, eidx, inv, xsrc, outp, ndst);
  };

  auto layer = [&](const float* ia, const float* ip, const float* it, int s, int l,
                   float* oa, float* op, float* ot){
    if (op){
      agg(rowptr_ap, eidx_ap, inv_ap, ia, aggP1, N_P);
      agg(rowptr_tp, eidx_tp, inv_tp, it, aggP2, N_P);
      gemm_mfma<3, 8, true, false><<<ceil_div(N_P, 128), 256, 0, stream>>>(
          aggP1, HI(IDL(s, l, 0)), LO(IDL(s, l, 0)),
          aggP2, HI(IDL(s, l, 3)), LO(IDL(s, l, 3)),
          ip,    HI(IDC(s, l)),    LO(IDC(s, l)),
          BC(s, l), nullptr, op, N_P);
    }
    if (oa){
      agg(rowptr_pa, eidx_pa, inv_pa, ip, aggA, N_A);
      gemm_mfma<2, 8, true, false><<<ceil_div(N_A, 128), 256, 0, stream>>>(
          aggA, HI(IDL(s, l, 1)), LO(IDL(s, l, 1)),
          ia,   HI(IDR(s, l, 1)), LO(IDR(s, l, 1)),
          nullptr, nullptr, nullptr,
          Bl(s, l, 1), nullptr, oa, N_A);
    }
    if (ot){
      agg(rowptr_pt, eidx_pt, inv_pt, ip, aggT, N_T);
      gemm_mfma<2, 8, true, false><<<ceil_div(N_T, 128), 256, 0, stream>>>(
          aggT, HI(IDL(s, l, 2)), LO(IDL(s, l, 2)),
          it,   HI(IDR(s, l, 2)), LO(IDR(s, l, 2)),
          nullptr, nullptr, nullptr,
          Bl(s, l, 2), nullptr, ot, N_T);
    }
  };

  float* out_logits = (float*)d_out;
  float* out_oa = out_logits + (size_t)N_A * OUT_DIM;
  float* out_op = out_oa + (size_t)N_A * D;
  float* out_ot = out_op + (size_t)N_P * D;

  // stack 0 (model) on raw features -> ma,mp,mt in A0,P0,T0
  layer(x_author, x_paper, x_term, 0, 0, A1, P1, T1);
  layer(A1, P1, T1, 0, 1, A0, P0, T0);
  // stack 1 (temperature) on ma,mp,mt; only author output of layer 1 needed
  layer(A0, P0, T0, 1, 0, A1, P1, T1);
  layer(A1, P1, T1, 1, 1, TA, nullptr, nullptr);
  // stack 2 (convs) on raw features -> directly into d_out
  layer(x_author, x_paper, x_term, 2, 0, A1, P1, T1);
  layer(A1, P1, T1, 2, 1, out_oa, out_op, out_ot);
  // temperature scalar per author, then logits GEMM with divide epilogue
  temp_kernel<<<ceil_div(N_A, 4), 256, 0, stream>>>(TA, wtc, temp, N_A);
  gemm_mfma<1, 4, false, true><<<ceil_div(N_A, 128), 256, 0, stream>>>(
      A0, HI(54), LO(54),
      nullptr, nullptr, nullptr,
      nullptr, nullptr, nullptr,
      lin_model_b, temp, out_logits, N_A);
}

// Round 4
// 2158.478 us; speedup vs baseline: 1.3989x; 1.1359x over previous
//
#include <hip/hip_runtime.h>
#include <cstdint>

#define N_A 40000
#define N_P 100000
#define N_T 20000
#define D 128
#define OUT_DIM 64
#define E_AP 500000
#define E_PT 800000

typedef __attribute__((ext_vector_type(8))) short bf16x8;
typedef __attribute__((ext_vector_type(4))) float f32x4;

static inline int ceil_div(int a, int b){ return (a + b - 1) / b; }

__device__ inline unsigned short f2bf(float f){
  uint32_t u = __builtin_bit_cast(uint32_t, f);
  uint32_t r = (u + 0x7FFFu + ((u >> 16) & 1u)) >> 16;
  return (unsigned short)r;
}
__device__ inline float bf2f(unsigned short h){
  uint32_t u = ((uint32_t)h) << 16;
  return __builtin_bit_cast(float, u);
}

// ---------------- CSR build ----------------
__global__ void hist_kernel(const int* __restrict__ dst, int E, int* __restrict__ cnt){
  int i = blockIdx.x * blockDim.x + threadIdx.x;
  if (i < E) atomicAdd(&cnt[dst[i]], 1);
}

__global__ void block_sums_kernel(const int* __restrict__ cnt, int n, int* __restrict__ bsums){
  __shared__ int red[256];
  int b = blockIdx.x, t = threadIdx.x;
  int base = b * 1024;
  int s = 0;
  for (int i = t; i < 1024; i += 256){ int idx = base + i; if (idx < n) s += cnt[idx]; }
  red[t] = s; __syncthreads();
  for (int off = 128; off > 0; off >>= 1){ if (t < off) red[t] += red[t + off]; __syncthreads(); }
  if (t == 0) bsums[b] = red[0];
}

__global__ void scan_bsums_kernel(int* bsums, int nb){
  __shared__ int sh[128];
  int t = threadIdx.x;
  int v = (t < nb) ? bsums[t] : 0;
  sh[t] = v; __syncthreads();
  int inc = v;
  for (int off = 1; off < 128; off <<= 1){
    int x = (t >= off) ? sh[t - off] : 0; __syncthreads();
    inc += x; sh[t] = inc; __syncthreads();
  }
  if (t < nb) bsums[t] = inc - v;   // exclusive
}

__global__ void scan_final_kernel(const int* __restrict__ cnt, int n, const int* __restrict__ bsums,
                                  int* __restrict__ rowptr, int E){
  __shared__ int sh[256];
  int b = blockIdx.x, t = threadIdx.x;
  int base = b * 1024 + t * 4;
  int v[4]; int s = 0;
  #pragma unroll
  for (int j = 0; j < 4; j++){ int idx = base + j; v[j] = (idx < n) ? cnt[idx] : 0; s += v[j]; }
  sh[t] = s; __syncthreads();
  int inc = s;
  for (int off = 1; off < 256; off <<= 1){
    int x = (t >= off) ? sh[t - off] : 0; __syncthreads();
    inc += x; sh[t] = inc; __syncthreads();
  }
  int run = inc - s + bsums[b];
  #pragma unroll
  for (int j = 0; j < 4; j++){ int idx = base + j; if (idx < n) rowptr[idx] = run; run += v[j]; }
  if (b == 0 && t == 0) rowptr[n] = E;
}

__global__ void cursor_inv_kernel(const int* __restrict__ rowptr, const int* __restrict__ cnt,
                                  int n, int* __restrict__ cursor, float* __restrict__ inv){
  int i = blockIdx.x * blockDim.x + threadIdx.x;
  if (i < n){
    cursor[i] = rowptr[i];
    int c = cnt[i];
    inv[i] = 1.0f / (float)(c > 0 ? c : 1);
  }
}

__global__ void fill_kernel(const int* __restrict__ src, const int* __restrict__ dst, int E,
                            int* __restrict__ cursor, int* __restrict__ eidx){
  int i = blockIdx.x * blockDim.x + threadIdx.x;
  if (i < E){
    int d = dst[i];
    int pos = atomicAdd(&cursor[d], 1);
    eidx[pos] = src[i];
  }
}

// ---------------- weight/bias combine for the paper relation pair ----------------
__global__ void combine_wr_kernel(const float* __restrict__ Wr, float* __restrict__ wrc){
  int i = blockIdx.x * blockDim.x + threadIdx.x;
  if (i < 6 * D * D){
    int sl = i >> 14; int off = i & (D * D - 1);
    wrc[i] = Wr[(size_t)(sl * 4 + 0) * D * D + off] + Wr[(size_t)(sl * 4 + 3) * D * D + off];
  }
}

__global__ void combine_bias_kernel(const float* __restrict__ bl, float* __restrict__ bcomb){
  int i = blockIdx.x * blockDim.x + threadIdx.x;
  if (i < 6 * D){
    int sl = i >> 7; int off = i & (D - 1);
    bcomb[i] = bl[(size_t)(sl * 4 + 0) * D + off] + bl[(size_t)(sl * 4 + 3) * D + off];
  }
}

// ---------------- weight split+pack into MFMA b-frag layout ----------------
// ids 0-23 = W_l, 24-47 = W_r, 48-53 = wrc, 54 = lin_model_W (N=64)
// dst[((kc*(N/16)+cf)*64 + lane)*8 + i] = bf16(W[(kc*32+(lane>>4)*8+i)*N + cf*16+(lane&15)])
__global__ __launch_bounds__(256)
void pack_weights_kernel(const float* __restrict__ W_l, const float* __restrict__ W_r,
                         const float* __restrict__ wrc, const float* __restrict__ linW,
                         unsigned short* __restrict__ packs){
  int id = blockIdx.x;
  const float* src; int N = 128;
  if (id < 24)      src = W_l + (size_t)id * 16384;
  else if (id < 48) src = W_r + (size_t)(id - 24) * 16384;
  else if (id < 54) src = wrc + (size_t)(id - 48) * 16384;
  else            { src = linW; N = 64; }
  unsigned short* dhi = packs + (size_t)id * 32768;
  unsigned short* dlo = dhi + 16384;
  int ncf = N / 16;
  int slots = 4 * ncf * 64;
  for (int s = threadIdx.x; s < slots; s += 256){
    int frag = s >> 6, l = s & 63;
    int kc = frag / ncf, cf = frag - kc * ncf;
    int kb = kc * 32 + ((l >> 4) * 8);
    int col = cf * 16 + (l & 15);
    bf16x8 hv, lv;
    #pragma unroll
    for (int i = 0; i < 8; ++i){
      float f = src[(size_t)(kb + i) * N + col];
      unsigned short h = f2bf(f);
      hv[i] = (short)h;
      lv[i] = (short)f2bf(f - bf2f(h));
    }
    *(bf16x8*)(dhi + (size_t)s * 8) = hv;
    *(bf16x8*)(dlo + (size_t)s * 8) = lv;
  }
}

// ---------------- mean aggregation: one wave per dst row, 8 edges in flight ----------------
__global__ __launch_bounds__(256)
void agg_mean_kernel(const int* __restrict__ rowptr, const int* __restrict__ eidx,
                     const float* __restrict__ inv, const float* __restrict__ xsrc,
                     float* __restrict__ out, int ndst){
  int w = (blockIdx.x * blockDim.x + threadIdx.x) >> 6;
  if (w >= ndst) return;
  int l = threadIdx.x & 63;
  int p = l >> 5, kk = l & 31;
  int beg = rowptr[w], end = rowptr[w + 1];
  float4 a0 = make_float4(0,0,0,0), a1 = make_float4(0,0,0,0);
  float4 a2 = make_float4(0,0,0,0), a3 = make_float4(0,0,0,0);
  int e = beg;
  for (; e + 8 <= end; e += 8){
    int s0 = eidx[e + p], s1 = eidx[e + 2 + p], s2 = eidx[e + 4 + p], s3 = eidx[e + 6 + p];
    float4 v0 = ((const float4*)(xsrc + (size_t)s0 * D))[kk];
    float4 v1 = ((const float4*)(xsrc + (size_t)s1 * D))[kk];
    float4 v2 = ((const float4*)(xsrc + (size_t)s2 * D))[kk];
    float4 v3 = ((const float4*)(xsrc + (size_t)s3 * D))[kk];
    a0.x += v0.x; a0.y += v0.y; a0.z += v0.z; a0.w += v0.w;
    a1.x += v1.x; a1.y += v1.y; a1.z += v1.z; a1.w += v1.w;
    a2.x += v2.x; a2.y += v2.y; a2.z += v2.z; a2.w += v2.w;
    a3.x += v3.x; a3.y += v3.y; a3.z += v3.z; a3.w += v3.w;
  }
  if (e + 4 <= end){
    int s0 = eidx[e + p], s1 = eidx[e + 2 + p];
    float4 v0 = ((const float4*)(xsrc + (size_t)s0 * D))[kk];
    float4 v1 = ((const float4*)(xsrc + (size_t)s1 * D))[kk];
    a0.x += v0.x; a0.y += v0.y; a0.z += v0.z; a0.w += v0.w;
    a1.x += v1.x; a1.y += v1.y; a1.z += v1.z; a1.w += v1.w;
    e += 4;
  }
  if (e + 2 <= end){
    int s0 = eidx[e + p];
    float4 v0 = ((const float4*)(xsrc + (size_t)s0 * D))[kk];
    a0.x += v0.x; a0.y += v0.y; a0.z += v0.z; a0.w += v0.w;
    e += 2;
  }
  if (e < end && p == 0){
    int s0 = eidx[e];
    float4 v0 = ((const float4*)(xsrc + (size_t)s0 * D))[kk];
    a0.x += v0.x; a0.y += v0.y; a0.z += v0.z; a0.w += v0.w;
  }
  a0.x += a1.x + a2.x + a3.x; a0.y += a1.y + a2.y + a3.y;
  a0.z += a1.z + a2.z + a3.z; a0.w += a1.w + a2.w + a3.w;
  a0.x += __shfl_xor(a0.x, 32); a0.y += __shfl_xor(a0.y, 32);
  a0.z += __shfl_xor(a0.z, 32); a0.w += __shfl_xor(a0.w, 32);
  if (p == 0){
    float iv = inv[w];
    float4 r; r.x = a0.x * iv; r.y = a0.y * iv; r.z = a0.z * iv; r.w = a0.w * iv;
    ((float4*)(out + (size_t)w * D))[kk] = r;
  }
}

// ---------------- MFMA split-bf16 GEMM, LDS-free, 64x64 wave tiles ----------------
// out[M, NCFT*16] = epi( sum_i in_i[M,128] @ W_i[128, NCFT*16] + bias )
// product = Ahi*Bhi + Alo*Bhi + Ahi*Blo (truncation split).
// 256 threads / 4 waves. NCFT=8: 2x2 wave grid, block tile 128x128.
// NCFT=4: 4x1 wave grid, block tile 256x64. Wave tile always 64 rows x 64 cols.
template<int NIN, int NCFT, bool RELU, bool DIV>
__global__ __launch_bounds__(256)
void gemm_mfma(const float* __restrict__ in0, const unsigned short* hi0, const unsigned short* lo0,
               const float* __restrict__ in1, const unsigned short* hi1, const unsigned short* lo1,
               const float* __restrict__ in2, const unsigned short* hi2, const unsigned short* lo2,
               const float* __restrict__ bias, const float* __restrict__ tdiv,
               float* __restrict__ out, int nrows){
  constexpr int WC = NCFT / 4;          // waves along N
  constexpr int WR = 4 / WC;            // waves along M
  const int tid    = threadIdx.x;
  const int w      = tid >> 6;
  const int l      = tid & 63;
  const int lane15 = l & 15;
  const int colg   = l >> 4;
  const int wr     = w / WC, wc = w % WC;
  const int rbase  = blockIdx.x * (WR * 64) + wr * 64;

  f32x4 acc[4][4];
  #pragma unroll
  for (int m = 0; m < 4; ++m)
    #pragma unroll
    for (int cf = 0; cf < 4; ++cf) acc[m][cf] = (f32x4){0.f, 0.f, 0.f, 0.f};

  const float* ins[3]          = {in0, in1, in2};
  const unsigned short* his[3] = {hi0, hi1, hi2};
  const unsigned short* los[3] = {lo0, lo1, lo2};

  #pragma unroll
  for (int inp = 0; inp < NIN; ++inp){
    const float* A = ins[inp];
    const bf16x8* WH = (const bf16x8*)his[inp];
    const bf16x8* WL = (const bf16x8*)los[inp];
    #pragma unroll
    for (int kc = 0; kc < 4; ++kc){
      // B frags for this wave's 4 col-fragments
      bf16x8 bh[4], bl[4];
      #pragma unroll
      for (int cf = 0; cf < 4; ++cf){
        int idx = (kc * NCFT + wc * 4 + cf) * 64 + l;
        bh[cf] = WH[idx];
        bl[cf] = WL[idx];
      }
      // A frags for 4 row-fragments, split fp32 -> bf16 hi/lo
      bf16x8 ah[4], al[4];
      #pragma unroll
      for (int m = 0; m < 4; ++m){
        int gr = rbase + m * 16 + lane15; if (gr >= nrows) gr = nrows - 1;
        const float4* p = (const float4*)(A + (size_t)gr * 128 + kc * 32 + colg * 8);
        float4 v0 = p[0], v1 = p[1];
        float fs[8] = {v0.x, v0.y, v0.z, v0.w, v1.x, v1.y, v1.z, v1.w};
        #pragma unroll
        for (int i = 0; i < 8; ++i){
          uint32_t u = __builtin_bit_cast(uint32_t, fs[i]);
          unsigned short h = (unsigned short)(u >> 16);            // truncation split
          float r = fs[i] - __builtin_bit_cast(float, u & 0xFFFF0000u);
          ah[m][i] = (short)h;
          al[m][i] = (short)(__builtin_bit_cast(uint32_t, r) >> 16);
        }
      }
      #pragma unroll
      for (int cf = 0; cf < 4; ++cf){
        #pragma unroll
        for (int m = 0; m < 4; ++m){
          acc[m][cf] = __builtin_amdgcn_mfma_f32_16x16x32_bf16(ah[m], bh[cf], acc[m][cf], 0, 0, 0);
          acc[m][cf] = __builtin_amdgcn_mfma_f32_16x16x32_bf16(al[m], bh[cf], acc[m][cf], 0, 0, 0);
          acc[m][cf] = __builtin_amdgcn_mfma_f32_16x16x32_bf16(ah[m], bl[cf], acc[m][cf], 0, 0, 0);
        }
      }
    }
  }

  // epilogue: D row = colg*4 + i (within 16-row frag), col = (wc*4+cf)*16 + lane15
  #pragma unroll
  for (int cf = 0; cf < 4; ++cf){
    int col = (wc * 4 + cf) * 16 + lane15;
    float bv = bias[col];
    #pragma unroll
    for (int m = 0; m < 4; ++m){
      #pragma unroll
      for (int i = 0; i < 4; ++i){
        int gr = rbase + m * 16 + colg * 4 + i;
        if (gr < nrows){
          float v = acc[m][cf][i] + bv;
          if (RELU) v = fmaxf(v, 0.f);
          if (DIV)  v = v / tdiv[gr];
          out[(size_t)gr * (NCFT * 16) + col] = v;
        }
      }
    }
  }
}

// ---------------- temperature fold ----------------
__global__ void wtc_kernel(const float* __restrict__ Wt, const float* __restrict__ bt,
                           const float* __restrict__ W2, const float* __restrict__ b2,
                           float* __restrict__ wtc){
  int k = threadIdx.x;
  if (k < 128){
    float s = 0.f;
    #pragma unroll 4
    for (int j = 0; j < 64; ++j) s += Wt[k * 64 + j] * W2[j];
    wtc[k] = s;
  }
  if (k == 0){
    float s = 0.f;
    for (int j = 0; j < 64; ++j) s += bt[j] * W2[j];
    wtc[128] = s + b2[0];
  }
}

__global__ __launch_bounds__(256)
void temp_kernel(const float* __restrict__ ta, const float* __restrict__ wtc,
                 float* __restrict__ temp, int n){
  int w = (blockIdx.x * blockDim.x + threadIdx.x) >> 6;
  if (w >= n) return;
  int l = threadIdx.x & 63;
  float2 v = ((const float2*)(ta + (size_t)w * D))[l];
  float2 c = ((const float2*)wtc)[l];
  float s = v.x * c.x + v.y * c.y;
  #pragma unroll
  for (int off = 32; off > 0; off >>= 1) s += __shfl_xor(s, off);
  if (l == 0) temp[w] = s + wtc[128];
}

// ---------------- host ----------------
extern "C" void kernel_launch(void* const* d_in, const int* in_sizes, int n_in,
                              void* d_out, int out_size, void* d_ws, size_t ws_size,
                              hipStream_t stream){
  const float* x_author    = (const float*)d_in[0];
  const float* x_paper     = (const float*)d_in[1];
  const float* x_term      = (const float*)d_in[2];
  const float* W_l         = (const float*)d_in[3];
  const float* b_l         = (const float*)d_in[4];
  const float* W_r         = (const float*)d_in[5];
  const float* lin_model_W = (const float*)d_in[6];
  const float* lin_model_b = (const float*)d_in[7];
  const float* lin_temp_W  = (const float*)d_in[8];
  const float* lin_temp_b  = (const float*)d_in[9];
  const float* lin2_W      = (const float*)d_in[10];
  const float* lin2_b      = (const float*)d_in[11];
  const int* src_ap = (const int*)d_in[12];
  const int* dst_ap = (const int*)d_in[13];
  const int* src_pa = (const int*)d_in[14];
  const int* dst_pa = (const int*)d_in[15];
  const int* src_pt = (const int*)d_in[16];
  const int* dst_pt = (const int*)d_in[17];
  const int* src_tp = (const int*)d_in[18];
  const int* dst_tp = (const int*)d_in[19];

  // ---- workspace carve ----
  char* wp = (char*)d_ws;
  auto alloc = [&](size_t bytes)->void*{
    void* r = (void*)wp; wp += (bytes + 255) & ~(size_t)255; return r;
  };
  int*   rowptr_ap = (int*)alloc((N_P + 1) * 4);
  int*   cnt_ap    = (int*)alloc(N_P * 4);
  int*   cur_ap    = (int*)alloc(N_P * 4);
  int*   eidx_ap   = (int*)alloc((size_t)E_AP * 4);
  float* inv_ap    = (float*)alloc(N_P * 4);
  int*   rowptr_pa = (int*)alloc((N_A + 1) * 4);
  int*   cnt_pa    = (int*)alloc(N_A * 4);
  int*   cur_pa    = (int*)alloc(N_A * 4);
  int*   eidx_pa   = (int*)alloc((size_t)E_AP * 4);
  float* inv_pa    = (float*)alloc(N_A * 4);
  int*   rowptr_pt = (int*)alloc((N_T + 1) * 4);
  int*   cnt_pt    = (int*)alloc(N_T * 4);
  int*   cur_pt    = (int*)alloc(N_T * 4);
  int*   eidx_pt   = (int*)alloc((size_t)E_PT * 4);
  float* inv_pt    = (float*)alloc(N_T * 4);
  int*   rowptr_tp = (int*)alloc((N_P + 1) * 4);
  int*   cnt_tp    = (int*)alloc(N_P * 4);
  int*   cur_tp    = (int*)alloc(N_P * 4);
  int*   eidx_tp   = (int*)alloc((size_t)E_PT * 4);
  float* inv_tp    = (float*)alloc(N_P * 4);
  int*   bsums     = (int*)alloc(1024 * 4);
  unsigned short* packs = (unsigned short*)alloc((size_t)55 * 32768 * 2);
  float* wrc   = (float*)alloc((size_t)6 * D * D * 4);
  float* bcomb = (float*)alloc((size_t)6 * D * 4);
  float* wtc   = (float*)alloc(129 * 4);
  float* temp  = (float*)alloc((size_t)N_A * 4);
  // shared aggregation buffers (live per layer-step)
  float* gA  = (float*)alloc((size_t)N_A * D * 4);
  float* gP1 = (float*)alloc((size_t)N_P * D * 4);
  float* gP2 = (float*)alloc((size_t)N_P * D * 4);
  float* gT  = (float*)alloc((size_t)N_T * D * 4);
  // activation banks
  float* A1 = (float*)alloc((size_t)N_A * D * 4);
  float* P1 = (float*)alloc((size_t)N_P * D * 4);
  float* T1 = (float*)alloc((size_t)N_T * D * 4);
  float* A2 = (float*)alloc((size_t)N_A * D * 4);
  float* P2 = (float*)alloc((size_t)N_P * D * 4);
  float* T2 = (float*)alloc((size_t)N_T * D * 4);
  // aliases: stack-2 bank is dead after its layer-1 aggs+GEMMs; reuse for ma/mp/mt
  float* A0 = A2;   // ma (live to the end, logits input)
  float* P0 = P2;   // mp
  float* T0 = T2;   // mt
  float* TA = P2;   // temperature-stack author out (written after P0 is dead)

  // ---- build CSR for the 4 relations ----
  auto build = [&](const int* src, const int* dst, int E, int n,
                   int* rowptr, int* cnt, int* cursor, int* eidx, float* inv){
    hipMemsetAsync(cnt, 0, (size_t)n * 4, stream);
    hist_kernel<<<ceil_div(E, 256), 256, 0, stream>>>(dst, E, cnt);
    int nb = ceil_div(n, 1024);
    block_sums_kernel<<<nb, 256, 0, stream>>>(cnt, n, bsums);
    scan_bsums_kernel<<<1, 128, 0, stream>>>(bsums, nb);
    scan_final_kernel<<<nb, 256, 0, stream>>>(cnt, n, bsums, rowptr, E);
    cursor_inv_kernel<<<ceil_div(n, 256), 256, 0, stream>>>(rowptr, cnt, n, cursor, inv);
    fill_kernel<<<ceil_div(E, 256), 256, 0, stream>>>(src, dst, E, cursor, eidx);
  };
  build(src_ap, dst_ap, E_AP, N_P, rowptr_ap, cnt_ap, cur_ap, eidx_ap, inv_ap);
  build(src_pa, dst_pa, E_AP, N_A, rowptr_pa, cnt_pa, cur_pa, eidx_pa, inv_pa);
  build(src_pt, dst_pt, E_PT, N_T, rowptr_pt, cnt_pt, cur_pt, eidx_pt, inv_pt);
  build(src_tp, dst_tp, E_PT, N_P, rowptr_tp, cnt_tp, cur_tp, eidx_tp, inv_tp);

  combine_wr_kernel<<<ceil_div(6 * D * D, 256), 256, 0, stream>>>(W_r, wrc);
  combine_bias_kernel<<<ceil_div(6 * D, 256), 256, 0, stream>>>(b_l, bcomb);
  pack_weights_kernel<<<55, 256, 0, stream>>>(W_l, W_r, wrc, lin_model_W, packs);
  wtc_kernel<<<1, 128, 0, stream>>>(lin_temp_W, lin_temp_b, lin2_W, lin2_b, wtc);

  auto HI = [&](int id){ return packs + (size_t)id * 32768; };
  auto LO = [&](int id){ return packs + (size_t)id * 32768 + 16384; };
  auto IDL = [&](int s, int l, int r){ return (s * 2 + l) * 4 + r; };
  auto IDR = [&](int s, int l, int r){ return 24 + (s * 2 + l) * 4 + r; };
  auto IDC = [&](int s, int l){ return 48 + s * 2 + l; };
  auto Bl  = [&](int s, int l, int r){ return b_l + (size_t)((s * 2 + l) * 4 + r) * D; };
  auto BC  = [&](int s, int l){ return bcomb + (size_t)(s * 2 + l) * D; };

  auto agg = [&](const int* rowptr, const int* eidx, const float* inv,
                 const float* xsrc, float* outp, int ndst){
    agg_mean_kernel<<<ceil_div(ndst, 4), 256, 0, stream>>>(rowptr, eidx, inv, xsrc, outp, ndst);
  };

  // aggregate all 4 relations from (ia, ip, it) into gA,gP1,gP2,gT
  auto agg_all = [&](const float* ia, const float* ip, const float* it){
    agg(rowptr_ap, eidx_ap, inv_ap, ia, gP1, N_P);
    agg(rowptr_tp, eidx_tp, inv_tp, it, gP2, N_P);
    agg(rowptr_pa, eidx_pa, inv_pa, ip, gA, N_A);
    agg(rowptr_pt, eidx_pt, inv_pt, ip, gT, N_T);
  };

  // GEMMs for one hetero layer reading gA,gP1,gP2,gT + x_dst
  auto gemms = [&](const float* ia, const float* ip, const float* it, int s, int l,
                   float* oa, float* op, float* ot){
    if (op) gemm_mfma<3, 8, true, false><<<ceil_div(N_P, 128), 256, 0, stream>>>(
        gP1, HI(IDL(s, l, 0)), LO(IDL(s, l, 0)),
        gP2, HI(IDL(s, l, 3)), LO(IDL(s, l, 3)),
        ip,  HI(IDC(s, l)),    LO(IDC(s, l)),
        BC(s, l), nullptr, op, N_P);
    if (oa) gemm_mfma<2, 8, true, false><<<ceil_div(N_A, 128), 256, 0, stream>>>(
        gA, HI(IDL(s, l, 1)), LO(IDL(s, l, 1)),
        ia, HI(IDR(s, l, 1)), LO(IDR(s, l, 1)),
        nullptr, nullptr, nullptr,
        Bl(s, l, 1), nullptr, oa, N_A);
    if (ot) gemm_mfma<2, 8, true, false><<<ceil_div(N_T, 128), 256, 0, stream>>>(
        gT, HI(IDL(s, l, 2)), LO(IDL(s, l, 2)),
        it, HI(IDR(s, l, 2)), LO(IDR(s, l, 2)),
        nullptr, nullptr, nullptr,
        Bl(s, l, 2), nullptr, ot, N_T);
  };

  float* out_logits = (float*)d_out;
  float* out_oa = out_logits + (size_t)N_A * OUT_DIM;
  float* out_op = out_oa + (size_t)N_A * D;
  float* out_ot = out_op + (size_t)N_P * D;

  // layer-0 aggregations of raw features -- shared by stack 0 and stack 2
  agg_all(x_author, x_paper, x_term);
  gemms(x_author, x_paper, x_term, 0, 0, A1, P1, T1);   // stack 0 layer 0
  gemms(x_author, x_paper, x_term, 2, 0, A2, P2, T2);   // stack 2 layer 0 (same aggs!)
  // stack 2 layer 1 -> final conv outputs
  agg_all(A2, P2, T2);
  gemms(A2, P2, T2, 2, 1, out_oa, out_op, out_ot);
  // stack 0 layer 1 -> ma, mp, mt (A2/P2/T2 now dead; A0/P0/T0 alias them)
  agg_all(A1, P1, T1);
  gemms(A1, P1, T1, 0, 1, A0, P0, T0);
  // stack 1 layer 0 on ma,mp,mt -> reuse bank 1
  agg_all(A0, P0, T0);
  gemms(A0, P0, T0, 1, 0, A1, P1, T1);
  // stack 1 layer 1: only the author output is needed (P0 dead -> TA aliases it)
  agg(rowptr_pa, eidx_pa, inv_pa, P1, gA, N_A);
  gemm_mfma<2, 8, true, false><<<ceil_div(N_A, 128), 256, 0, stream>>>(
      gA, HI(IDL(1, 1, 1)), LO(IDL(1, 1, 1)),
      A1, HI(IDR(1, 1, 1)), LO(IDR(1, 1, 1)),
      nullptr, nullptr, nullptr,
      Bl(1, 1, 1), nullptr, TA, N_A);
  // temperature scalar per author, then logits GEMM with divide epilogue
  temp_kernel<<<ceil_div(N_A, 4), 256, 0, stream>>>(TA, wtc, temp, N_A);
  gemm_mfma<1, 4, false, true><<<ceil_div(N_A, 256), 256, 0, stream>>>(
      A0, HI(54), LO(54),
      nullptr, nullptr, nullptr,
      nullptr, nullptr, nullptr,
      lin_model_b, temp, out_logits, N_A);
}